// Round 6
// baseline (17.640 us; speedup 1.0000x reference)
//
#include <hip/hip_runtime.h>

#define TPB 256

// v2f: component .x = pair A, .y = pair B.  All fma-shaped math is done on
// <2 x float> so the backend emits packed v_pk_*_f32 (VOP3P); compares and
// selects have no packed form and are done componentwise (zero loss).
typedef float v2f __attribute__((ext_vector_type(2)));

__device__ __forceinline__ v2f mk2(float a, float b) { v2f r; r.x = a; r.y = b; return r; }
__device__ __forceinline__ v2f rcp2(v2f v) {
    return mk2(__builtin_amdgcn_rcpf(v.x), __builtin_amdgcn_rcpf(v.y));
}
__device__ __forceinline__ v2f max2(v2f a, v2f b) { return mk2(fmaxf(a.x, b.x), fmaxf(a.y, b.y)); }
__device__ __forceinline__ v2f abs2(v2f a)        { return mk2(fabsf(a.x), fabsf(a.y)); }

// Sum over the 4 edges (A->B) of CCW polygon V of (t1-t0)*cross(A,B), where
// [t0,t1] ⊆ [0,1] is the edge's parameter interval inside the CCW clip quad
// with lines d(X) = ex*X.y - ey*X.x - c0 >= 0.  Summing (P clipped by Q) +
// (Q clipped by P) gives 2*area(P∩Q).
//
// Interval form: d(t) = dA - t*D, D = dA-dB.  Degenerate |D|<1e-12 -> Dt=+1e-12
// is handled correctly WITHOUT a sign-aware eps: dA>=0 gives t=+huge (upper
// bound, non-binding ✓); dA<0 gives t=-huge (upper bound -> empty interval ✓).
// Exact-tie (d==0) segments differ from SH by a zero-length piece only.
__device__ __forceinline__ v2f edge_pieces2(
    const v2f (&vx)[4], const v2f (&vy)[4],
    const v2f (&ex)[4], const v2f (&ey)[4], const v2f (&c0)[4])
{
    v2f d[4][4];
    #pragma unroll
    for (int i = 0; i < 4; ++i)
        #pragma unroll
        for (int k = 0; k < 4; ++k)
            d[i][k] = ex[k] * vy[i] - ey[k] * vx[i] - c0[k];   // 2 pk-fma

    v2f sum = mk2(0.f, 0.f);
    #pragma unroll
    for (int i = 0; i < 4; ++i) {
        const int j = (i + 1) & 3;
        const v2f cr = vx[i] * vy[j] - vy[i] * vx[j];
        v2f lo = mk2(0.f, 0.f), hi = mk2(1.f, 1.f);
        #pragma unroll
        for (int k = 0; k < 4; ++k) {
            const v2f dA = d[i][k], dB = d[j][k];
            const v2f D  = dA - dB;
            v2f Dt;
            Dt.x = (fabsf(D.x) < 1e-12f) ? 1e-12f : D.x;
            Dt.y = (fabsf(D.y) < 1e-12f) ? 1e-12f : D.y;
            const v2f t = dA * rcp2(Dt);
            const bool ux = Dt.x > 0.f, uy = Dt.y > 0.f;
            hi.x = ux ? fminf(hi.x, t.x) : hi.x;
            lo.x = ux ? lo.x : fmaxf(lo.x, t.x);
            hi.y = uy ? fminf(hi.y, t.y) : hi.y;
            lo.y = uy ? lo.y : fmaxf(lo.y, t.y);
        }
        sum += max2(hi - lo, mk2(0.f, 0.f)) * cr;
    }
    return sum;
}

__device__ __forceinline__ void make_lines2(
    const v2f (&vx)[4], const v2f (&vy)[4],
    v2f (&ex)[4], v2f (&ey)[4], v2f (&c0)[4])
{
    #pragma unroll
    for (int k = 0; k < 4; ++k) {
        const int k2 = (k + 1) & 3;
        ex[k] = vx[k2] - vx[k];
        ey[k] = vy[k2] - vy[k];
        c0[k] = ex[k] * vy[k] - ey[k] * vx[k];
    }
}

// force CCW per component: swap v0<->v3, v1<->v2 where signed area < 0
__device__ __forceinline__ void ccw2(v2f (&qx)[4], v2f (&qy)[4], const v2f a_s)
{
    const bool cx = a_s.x < 0.f, cy = a_s.y < 0.f;
    #define SWP(u, v, c) { const float t_ = (c) ? (v) : (u); (v) = (c) ? (u) : (v); (u) = t_; }
    SWP(qx[0].x, qx[3].x, cx)  SWP(qy[0].x, qy[3].x, cx)
    SWP(qx[1].x, qx[2].x, cx)  SWP(qy[1].x, qy[2].x, cx)
    SWP(qx[0].y, qx[3].y, cy)  SWP(qy[0].y, qy[3].y, cy)
    SWP(qx[1].y, qx[2].y, cy)  SWP(qy[1].y, qy[2].y, cy)
    #undef SWP
}

// One thread = two ADJACENT pairs (2t, 2t+1): 64 B contiguous per lane per
// tensor.  IoU is invariant under the reference's per-image (W*x,H*y) scaling
// (all areas scale by W*H), so image_size is not needed.
__global__ __launch_bounds__(TPB) void obb_pair_kernel(
    const float4* __restrict__ pred, const float4* __restrict__ gt,
    const int* __restrict__ mask, float2* __restrict__ partial,
    int npair2, int total)
{
    __shared__ float red_l[TPB / 64], red_m[TPB / 64];

    const int tp = blockIdx.x * TPB + threadIdx.x;
    float lacc = 0.f, macc = 0.f;

    if (tp < npair2) {
        const int iA = 2 * tp;
        const bool vB = (iA + 1) < total;
        const int iB = vB ? (iA + 1) : iA;          // clamp; mask kills dup

        const float4 a0 = pred[2 * iA], a1 = pred[2 * iA + 1];
        const float4 b0 = pred[2 * iB], b1 = pred[2 * iB + 1];
        const float4 ga0 = gt[2 * iA],  ga1 = gt[2 * iA + 1];
        const float4 gb0 = gt[2 * iB],  gb1 = gt[2 * iB + 1];

        const int2 mm = vB ? ((const int2*)mask)[tp] : make_int2(mask[iA], 0);
        const v2f mval = mk2(mm.x != 0 ? 1.f : 0.f, mm.y != 0 ? 1.f : 0.f);

        v2f px[4], py[4], gx[4], gy[4];
        px[0] = mk2(a0.x, b0.x);  py[0] = mk2(a0.y, b0.y);
        px[1] = mk2(a0.z, b0.z);  py[1] = mk2(a0.w, b0.w);
        px[2] = mk2(a1.x, b1.x);  py[2] = mk2(a1.y, b1.y);
        px[3] = mk2(a1.z, b1.z);  py[3] = mk2(a1.w, b1.w);
        gx[0] = mk2(ga0.x, gb0.x);  gy[0] = mk2(ga0.y, gb0.y);
        gx[1] = mk2(ga0.z, gb0.z);  gy[1] = mk2(ga0.w, gb0.w);
        gx[2] = mk2(ga1.x, gb1.x);  gy[2] = mk2(ga1.y, gb1.y);
        gx[3] = mk2(ga1.z, gb1.z);  gy[3] = mk2(ga1.w, gb1.w);

        v2f ap_s = mk2(0.f, 0.f), ag_s = mk2(0.f, 0.f);   // shoelace (x2)
        #pragma unroll
        for (int i = 0; i < 4; ++i) {
            const int j = (i + 1) & 3;
            ap_s += px[i] * py[j] - py[i] * px[j];
            ag_s += gx[i] * gy[j] - gy[i] * gx[j];
        }
        ap_s = ap_s * mk2(0.5f, 0.5f);
        ag_s = ag_s * mk2(0.5f, 0.5f);

        ccw2(px, py, ap_s);
        ccw2(gx, gy, ag_s);

        v2f pex[4], pey[4], pc0[4], gex[4], gey[4], gc0[4];
        make_lines2(px, py, pex, pey, pc0);
        make_lines2(gx, gy, gex, gey, gc0);

        const v2f a2 = edge_pieces2(px, py, gex, gey, gc0)   // P edges in Q
                     + edge_pieces2(gx, gy, pex, pey, pc0);  // Q edges in P

        const v2f inter = abs2(a2) * mk2(0.5f, 0.5f);
        const v2f uni   = abs2(ap_s) + abs2(ag_s) - inter;
        v2f iou;
        iou.x = (uni.x > 0.f) ? inter.x * __builtin_amdgcn_rcpf(uni.x) : 0.f;
        iou.y = (uni.y > 0.f) ? inter.y * __builtin_amdgcn_rcpf(uni.y) : 0.f;

        lacc = (1.f - iou.x) * mval.x + (1.f - iou.y) * mval.y;
        macc = mval.x + mval.y;
    }

    // deterministic block reduction: wave shuffle then cross-wave LDS
    float l = lacc, m = macc;
    #pragma unroll
    for (int off = 32; off > 0; off >>= 1) {
        l += __shfl_down(l, off, 64);
        m += __shfl_down(m, off, 64);
    }
    const int wid  = threadIdx.x >> 6;
    const int lane = threadIdx.x & 63;
    if (lane == 0) { red_l[wid] = l; red_m[wid] = m; }
    __syncthreads();
    if (threadIdx.x == 0) {
        const float L = red_l[0] + red_l[1] + red_l[2] + red_l[3];
        const float M = red_m[0] + red_m[1] + red_m[2] + red_m[3];
        partial[blockIdx.x] = make_float2(L, M);
    }
}

__global__ __launch_bounds__(256) void obb_finalize(
    const float2* __restrict__ partial, int nb, float* __restrict__ out)
{
    __shared__ double sl[256], sm[256];
    double l = 0.0, m = 0.0;
    for (int i = threadIdx.x; i < nb; i += 256) {
        const float2 v = partial[i];
        l += (double)v.x;
        m += (double)v.y;
    }
    sl[threadIdx.x] = l;
    sm[threadIdx.x] = m;
    __syncthreads();
    for (int s = 128; s > 0; s >>= 1) {
        if (threadIdx.x < s) {
            sl[threadIdx.x] += sl[threadIdx.x + s];
            sm[threadIdx.x] += sm[threadIdx.x + s];
        }
        __syncthreads();
    }
    if (threadIdx.x == 0) {
        const double nval = sm[0];
        const double mean = sl[0] / (nval > 1.0 ? nval : 1.0);
        out[0] = (nval > 0.0) ? (float)mean : 0.f;
    }
}

extern "C" void kernel_launch(void* const* d_in, const int* in_sizes, int n_in,
                              void* d_out, int out_size, void* d_ws, size_t ws_size,
                              hipStream_t stream)
{
    const float4* pred = (const float4*)d_in[0];   // (B,N,8) f32
    const float4* gt   = (const float4*)d_in[1];   // (B,N,8) f32
    const int* mask    = (const int*)d_in[3];      // (B,N) bool->i32
    float* out = (float*)d_out;                    // scalar f32

    const int total  = in_sizes[0] / 8;            // B*N
    const int npair2 = (total + 1) / 2;
    const int blocks = (npair2 + TPB - 1) / TPB;

    float2* partial = (float2*)d_ws;               // blocks * 8 B

    obb_pair_kernel<<<blocks, TPB, 0, stream>>>(pred, gt, mask, partial,
                                                npair2, total);
    obb_finalize<<<1, 256, 0, stream>>>(partial, blocks, out);
}

// Round 7
// 17.205 us; speedup vs baseline: 1.0253x; 1.0253x over previous
//
#include <hip/hip_runtime.h>

#define TPB 256

// v2f: component .x = pair A, .y = pair B (two independent box pairs/thread).
typedef float v2f __attribute__((ext_vector_type(2)));

__device__ __forceinline__ v2f mk2(float a, float b) { v2f r; r.x = a; r.y = b; return r; }
__device__ __forceinline__ v2f abs2(v2f a) { return mk2(fabsf(a.x), fabsf(a.y)); }

// 2*area(P∩Q) for convex CCW quads via boundary line-integral:
//   2A = Σ_{edges e of P} (t1-t0)_e * cross(A_e,B_e)  +  same over Q edges,
// where [t0,t1] ⊆ [0,1] is the edge's parameter interval inside the other quad.
//
// KEY IDENTITY (shared denominators): for P-edge i vs Q-line k the interval
// denominator is D_P = dP[i][k]-dP[j][k] = -cross(eQ_k, eP_i) = -C[i][k];
// for Q-edge k vs P-line i it is D_Q = +C[i][k].  So ONE protected reciprocal
// R[i][k] = rcp(C~) serves both passes:  tP = -dP[i][k]*R,  tQ = +dQ[k][i]*R,
// with bound-type from flag = (C~ > 0): Q-pass upper iff flag, P-pass upper
// iff !flag.  Degenerate |C|<1e-12 -> C~=+1e-12: both passes reduce to the
// correct keep/empty behavior by sign of dA (t = ±huge, checked both ways).
__global__ __launch_bounds__(TPB) void obb_pair_kernel(
    const float4* __restrict__ pred, const float4* __restrict__ gt,
    const int* __restrict__ mask, float2* __restrict__ partial,
    int npair2, int total)
{
    __shared__ float red_l[TPB / 64], red_m[TPB / 64];

    const int tp = blockIdx.x * TPB + threadIdx.x;
    float lacc = 0.f, macc = 0.f;

    if (tp < npair2) {
        const int iA = 2 * tp;
        const bool vB = (iA + 1) < total;
        const int iB = vB ? (iA + 1) : iA;          // clamp; mask kills dup

        const float4 a0 = pred[2 * iA], a1 = pred[2 * iA + 1];
        const float4 b0 = pred[2 * iB], b1 = pred[2 * iB + 1];
        const float4 ga0 = gt[2 * iA],  ga1 = gt[2 * iA + 1];
        const float4 gb0 = gt[2 * iB],  gb1 = gt[2 * iB + 1];

        const int2 mm = vB ? ((const int2*)mask)[tp] : make_int2(mask[iA], 0);
        const v2f mval = mk2(mm.x != 0 ? 1.f : 0.f, mm.y != 0 ? 1.f : 0.f);

        v2f px[4], py[4], gx[4], gy[4];
        px[0] = mk2(a0.x, b0.x);   py[0] = mk2(a0.y, b0.y);
        px[1] = mk2(a0.z, b0.z);   py[1] = mk2(a0.w, b0.w);
        px[2] = mk2(a1.x, b1.x);   py[2] = mk2(a1.y, b1.y);
        px[3] = mk2(a1.z, b1.z);   py[3] = mk2(a1.w, b1.w);
        gx[0] = mk2(ga0.x, gb0.x); gy[0] = mk2(ga0.y, gb0.y);
        gx[1] = mk2(ga0.z, gb0.z); gy[1] = mk2(ga0.w, gb0.w);
        gx[2] = mk2(ga1.x, gb1.x); gy[2] = mk2(ga1.y, gb1.y);
        gx[3] = mk2(ga1.z, gb1.z); gy[3] = mk2(ga1.w, gb1.w);

        // shoelace signed areas (IoU is invariant to the per-image W/H scale,
        // so image_size is dropped entirely)
        v2f ap_s = mk2(0.f, 0.f), ag_s = mk2(0.f, 0.f);
        #pragma unroll
        for (int i = 0; i < 4; ++i) {
            const int j = (i + 1) & 3;
            ap_s += px[i] * py[j] - py[i] * px[j];
            ag_s += gx[i] * gy[j] - gy[i] * gx[j];
        }
        ap_s *= 0.5f;  ag_s *= 0.5f;

        // force CCW per component (swap v0<->v3, v1<->v2 where area < 0)
        {
            const bool cx = ap_s.x < 0.f, cy = ap_s.y < 0.f;
            const bool dx = ag_s.x < 0.f, dy = ag_s.y < 0.f;
            #define SWP(u, v, c) { const float t_ = (c) ? (v) : (u); (v) = (c) ? (u) : (v); (u) = t_; }
            SWP(px[0].x, px[3].x, cx)  SWP(py[0].x, py[3].x, cx)
            SWP(px[1].x, px[2].x, cx)  SWP(py[1].x, py[2].x, cx)
            SWP(px[0].y, px[3].y, cy)  SWP(py[0].y, py[3].y, cy)
            SWP(px[1].y, px[2].y, cy)  SWP(py[1].y, py[2].y, cy)
            SWP(gx[0].x, gx[3].x, dx)  SWP(gy[0].x, gy[3].x, dx)
            SWP(gx[1].x, gx[2].x, dx)  SWP(gy[1].x, gy[2].x, dx)
            SWP(gx[0].y, gx[3].y, dy)  SWP(gy[0].y, gy[3].y, dy)
            SWP(gx[1].y, gx[2].y, dy)  SWP(gy[1].y, gy[2].y, dy)
            #undef SWP
        }

        // edge vectors + line constants: d(X) = e.x*X.y - e.y*X.x - c0
        v2f pex[4], pey[4], pc0[4], gex[4], gey[4], gc0[4];
        #pragma unroll
        for (int k = 0; k < 4; ++k) {
            const int k2 = (k + 1) & 3;
            pex[k] = px[k2] - px[k];  pey[k] = py[k2] - py[k];
            pc0[k] = pex[k] * py[k] - pey[k] * px[k];
            gex[k] = gx[k2] - gx[k];  gey[k] = gy[k2] - gy[k];
            gc0[k] = gex[k] * gy[k] - gey[k] * gx[k];
        }

        // distance matrices: dP[i][k] = P-vertex i vs Q-line k (A-endpoint of
        // P-edge i); dQ[k][i] = Q-vertex k vs P-line i (A-endpoint of Q-edge k)
        v2f dP[4][4], dQ[4][4];
        #pragma unroll
        for (int i = 0; i < 4; ++i)
            #pragma unroll
            for (int k = 0; k < 4; ++k) {
                dP[i][k] = gex[k] * py[i] - gey[k] * px[i] - gc0[k];
                dQ[k][i] = pex[i] * gy[k] - pey[i] * gx[k] - pc0[i];
            }

        v2f loP[4], hiP[4], loQ[4], hiQ[4];
        #pragma unroll
        for (int i = 0; i < 4; ++i) {
            loP[i] = mk2(0.f, 0.f);  hiP[i] = mk2(1.f, 1.f);
            loQ[i] = mk2(0.f, 0.f);  hiQ[i] = mk2(1.f, 1.f);
        }

        #pragma unroll
        for (int i = 0; i < 4; ++i) {
            #pragma unroll
            for (int k = 0; k < 4; ++k) {
                v2f C = gex[k] * pey[i] - gey[k] * pex[i];  // shared denominator
                C.x = (fabsf(C.x) < 1e-12f) ? 1e-12f : C.x;
                C.y = (fabsf(C.y) < 1e-12f) ? 1e-12f : C.y;
                const v2f R  = mk2(__builtin_amdgcn_rcpf(C.x),
                                   __builtin_amdgcn_rcpf(C.y));
                const v2f tP = -dP[i][k] * R;               // dA/(dA-dB), P pass
                const v2f tQ =  dQ[k][i] * R;               // dA/(dA-dB), Q pass
                const bool fx = C.x > 0.f, fy = C.y > 0.f;
                // P-edge i: upper bound iff !flag
                hiP[i].x = fx ? hiP[i].x : fminf(hiP[i].x, tP.x);
                loP[i].x = fx ? fmaxf(loP[i].x, tP.x) : loP[i].x;
                hiP[i].y = fy ? hiP[i].y : fminf(hiP[i].y, tP.y);
                loP[i].y = fy ? fmaxf(loP[i].y, tP.y) : loP[i].y;
                // Q-edge k: upper bound iff flag
                hiQ[k].x = fx ? fminf(hiQ[k].x, tQ.x) : hiQ[k].x;
                loQ[k].x = fx ? loQ[k].x : fmaxf(loQ[k].x, tQ.x);
                hiQ[k].y = fy ? fminf(hiQ[k].y, tQ.y) : hiQ[k].y;
                loQ[k].y = fy ? loQ[k].y : fmaxf(loQ[k].y, tQ.y);
            }
        }

        // 2*area(P∩Q): clipped-length * cross(A,B), both polygons' edges
        v2f a2 = mk2(0.f, 0.f);
        #pragma unroll
        for (int e = 0; e < 4; ++e) {
            const int j = (e + 1) & 3;
            const v2f crP = px[e] * py[j] - py[e] * px[j];
            const v2f crQ = gx[e] * gy[j] - gy[e] * gx[j];
            v2f lenP = hiP[e] - loP[e], lenQ = hiQ[e] - loQ[e];
            lenP.x = fmaxf(lenP.x, 0.f);  lenP.y = fmaxf(lenP.y, 0.f);
            lenQ.x = fmaxf(lenQ.x, 0.f);  lenQ.y = fmaxf(lenQ.y, 0.f);
            a2 += lenP * crP + lenQ * crQ;
        }

        const v2f inter = abs2(a2) * 0.5f;
        const v2f uni   = abs2(ap_s) + abs2(ag_s) - inter;
        v2f iou;
        iou.x = (uni.x > 0.f) ? inter.x * __builtin_amdgcn_rcpf(uni.x) : 0.f;
        iou.y = (uni.y > 0.f) ? inter.y * __builtin_amdgcn_rcpf(uni.y) : 0.f;

        lacc = (1.f - iou.x) * mval.x + (1.f - iou.y) * mval.y;
        macc = mval.x + mval.y;
    }

    // deterministic block reduction: wave shuffle then cross-wave LDS
    float l = lacc, m = macc;
    #pragma unroll
    for (int off = 32; off > 0; off >>= 1) {
        l += __shfl_down(l, off, 64);
        m += __shfl_down(m, off, 64);
    }
    const int wid  = threadIdx.x >> 6;
    const int lane = threadIdx.x & 63;
    if (lane == 0) { red_l[wid] = l; red_m[wid] = m; }
    __syncthreads();
    if (threadIdx.x == 0) {
        const float L = red_l[0] + red_l[1] + red_l[2] + red_l[3];
        const float M = red_m[0] + red_m[1] + red_m[2] + red_m[3];
        partial[blockIdx.x] = make_float2(L, M);
    }
}

// 1024 threads, 1 partial per thread -> double shuffle-reduce (fixed order,
// deterministic), cross-wave via LDS.
__global__ __launch_bounds__(1024) void obb_finalize(
    const float2* __restrict__ partial, int nb, float* __restrict__ out)
{
    __shared__ double sl[16], sm[16];
    double l = 0.0, m = 0.0;
    for (int i = threadIdx.x; i < nb; i += 1024) {
        const float2 v = partial[i];
        l += (double)v.x;
        m += (double)v.y;
    }
    #pragma unroll
    for (int off = 32; off > 0; off >>= 1) {
        l += __shfl_down(l, off, 64);
        m += __shfl_down(m, off, 64);
    }
    const int wid  = threadIdx.x >> 6;
    const int lane = threadIdx.x & 63;
    if (lane == 0) { sl[wid] = l; sm[wid] = m; }
    __syncthreads();
    if (threadIdx.x == 0) {
        double L = 0.0, M = 0.0;
        #pragma unroll
        for (int w = 0; w < 16; ++w) { L += sl[w]; M += sm[w]; }
        const double mean = L / (M > 1.0 ? M : 1.0);
        out[0] = (M > 0.0) ? (float)mean : 0.f;
    }
}

extern "C" void kernel_launch(void* const* d_in, const int* in_sizes, int n_in,
                              void* d_out, int out_size, void* d_ws, size_t ws_size,
                              hipStream_t stream)
{
    const float4* pred = (const float4*)d_in[0];   // (B,N,8) f32
    const float4* gt   = (const float4*)d_in[1];   // (B,N,8) f32
    const int* mask    = (const int*)d_in[3];      // (B,N) bool->i32
    float* out = (float*)d_out;                    // scalar f32

    const int total  = in_sizes[0] / 8;            // B*N
    const int npair2 = (total + 1) / 2;
    const int blocks = (npair2 + TPB - 1) / TPB;

    float2* partial = (float2*)d_ws;               // blocks * 8 B

    obb_pair_kernel<<<blocks, TPB, 0, stream>>>(pred, gt, mask, partial,
                                                npair2, total);
    obb_finalize<<<1, 1024, 0, stream>>>(partial, blocks, out);
}